// Round 13
// baseline (495.205 us; speedup 1.0000x reference)
//
#include <hip/hip_runtime.h>

typedef __bf16 bf16_t;
typedef __bf16 bf16x8 __attribute__((ext_vector_type(8)));
typedef __bf16 bf16x4 __attribute__((ext_vector_type(4)));
typedef float  f32x4  __attribute__((ext_vector_type(4)));
typedef unsigned u32x4 __attribute__((ext_vector_type(4)));

#define SEQ    1024
#define DMODEL 4096
#define NHQ    32
#define NHKV   8
#define HDIM   128

// async global->LDS, 16B per lane; LDS dest must be linear (base + lane*16)
#define GLOAD_LDS16(g, l)                                                  \
    __builtin_amdgcn_global_load_lds(                                      \
        (const __attribute__((address_space(1))) unsigned int*)(g),        \
        (__attribute__((address_space(3))) unsigned int*)(l), 16, 0, 0)

// ---------------------------------------------------------------------------
// fp32 -> bf16 convert, 8 elems/thread
// ---------------------------------------------------------------------------
__global__ __launch_bounds__(256)
void f2b(const float* __restrict__ in, bf16_t* __restrict__ out, int n8)
{
    int i = blockIdx.x * 256 + threadIdx.x;
    if (i >= n8) return;
    const float4* p = (const float4*)in + 2 * (size_t)i;
    float4 a = p[0], b = p[1];
    bf16x8 o;
    o[0] = (bf16_t)a.x; o[1] = (bf16_t)a.y; o[2] = (bf16_t)a.z; o[3] = (bf16_t)a.w;
    o[4] = (bf16_t)b.x; o[5] = (bf16_t)b.y; o[6] = (bf16_t)b.z; o[7] = (bf16_t)b.w;
    *((bf16x8*)out + i) = o;
}

// ---------------------------------------------------------------------------
// 256x256 8-wave GEMM -- 8-phase, BK=64, dbuf over even/odd K-tiles.
// PIPELINED FRAGMENT READS (round-13 = round-12 + race fix): phase i issues
// the ds_reads for phase i+1 BEFORE its own MFMA cluster, via inline-asm
// ds_read_b128 + counted lgkmcnt(N) (DS retires in order -> MFMA waits only
// for the PREVIOUS phase's reads). LDS pipe fills while the wave grinds
// MFMAs, breaking the in-order-issue serialization (4481 cy/K-tile ~ LDS
// 2304 + MFMA 2066 summed).
// RACE FIX vs round-12: vmcnt(2) is PER-WAVE -- it must execute BEFORE the
// barrier that precedes cross-wave reads of the staged buffer (each wave
// certifies its own gload_lds landed; the barrier publishes). Round-12 had
// it after the barrier -> waves read rows whose stager hadn't vmcnt'd yet
// (absmax 0.035). Now: WVM2 at END of P3/P7 (after MFMA, before BAR).
// Hazard audit (stage target vs in-flight reads): P1 SA(b1,h0) vs P8-prev
// reads of buf0 tile T - disjoint; P2 SA(b1,h1) vs P1 b1-reads (buf0 B h1)
// - different buffer; P3 SB(b0,h0) overwrites buf0 B h0, last read P8-prev,
// retired by reader's P1 lgkmcnt(4) < BAR_P2 < stage; P7 SB(b1,h0)
// overwrites buf1 B h0, last read P4, retired by P5 lgkmcnt(4) < BAR_P6.
// Buffer-landed: end-P3 vmcnt(2) completes {prevP7.SB,prevP8.SB,P1.SA,
// P2.SA} = ALL of tile T+1 before BAR_P4; end-P7 symmetric for tile T+2.
// ---------------------------------------------------------------------------
#define MFMA_(a, b, c) __builtin_amdgcn_mfma_f32_16x16x32_bf16(a, b, c, 0, 0, 0)
#define BAR    __builtin_amdgcn_s_barrier()
#define SCB    __builtin_amdgcn_sched_barrier(0)
#define PRIO1  __builtin_amdgcn_s_setprio(1)
#define PRIO0  __builtin_amdgcn_s_setprio(0)
#define WVM2   do { asm volatile("s_waitcnt vmcnt(2)" ::: "memory"); SCB; } while (0)
#define WLGK(N) do { asm volatile("s_waitcnt lgkmcnt(" N ")" ::: "memory"); SCB; } while (0)
#define BC8(x) __builtin_bit_cast(bf16x8, x)

#define DSR(dst, a, OFF) \
    asm volatile("ds_read_b128 %0, %1 offset:" OFF : "=v"(dst) : "v"(a))

#define LDA_ASM(DST, bufo, mh) do {                                        \
    unsigned aA_ = aBase + (bufo) + (mh) * 4096;                           \
    DSR(DST[0][0], aA_, "0");     DSR(DST[0][1], aA_, "16384");            \
    DSR(DST[1][0], aA_, "1024");  DSR(DST[1][1], aA_, "17408");            \
    DSR(DST[2][0], aA_, "2048");  DSR(DST[2][1], aA_, "18432");            \
    DSR(DST[3][0], aA_, "3072");  DSR(DST[3][1], aA_, "19456");            \
} while (0)
#define LDB_ASM(DST, bufo, nh) do {                                        \
    unsigned bA_ = bBase + (bufo) + (nh) * 2048;                           \
    DSR(DST[0][0], bA_, "0");     DSR(DST[0][1], bA_, "16384");            \
    DSR(DST[1][0], bA_, "1024");  DSR(DST[1][1], bA_, "17408");            \
} while (0)

#define SA(bufo, half, ktb)  do {                                          \
    const char* g_ = ((half) ? aS1 : aS0) + (ktb);                         \
    GLOAD_LDS16(g_,      sd + (bufo) + (half) * 8192);                     \
    GLOAD_LDS16(g_ + 64, sd + (bufo) + (half) * 8192 + 16384);             \
} while (0)
#define SB(bufo, half, ktb)  do {                                          \
    const char* g_ = ((half) ? bS1 : bS0) + (ktb);                         \
    GLOAD_LDS16(g_,      sd + (bufo) + 32768 + (half) * 8192);             \
    GLOAD_LDS16(g_ + 64, sd + (bufo) + 32768 + (half) * 8192 + 16384);     \
} while (0)

#define MMQ2(mlo, AFS, BFS, nlo) do { _Pragma("unroll")                    \
    for (int j = 0; j < 4; ++j) {                                          \
        acc[(mlo)+j][(nlo)  ] = MFMA_(BC8(AFS[j][0]), BC8(BFS[0][0]), acc[(mlo)+j][(nlo)  ]); \
        acc[(mlo)+j][(nlo)  ] = MFMA_(BC8(AFS[j][1]), BC8(BFS[0][1]), acc[(mlo)+j][(nlo)  ]); \
        acc[(mlo)+j][(nlo)+1] = MFMA_(BC8(AFS[j][0]), BC8(BFS[1][0]), acc[(mlo)+j][(nlo)+1]); \
        acc[(mlo)+j][(nlo)+1] = MFMA_(BC8(AFS[j][1]), BC8(BFS[1][1]), acc[(mlo)+j][(nlo)+1]); \
    } } while (0)

template<bool OUT_F32>
__global__ __launch_bounds__(512, 2)
void gemm256(const bf16_t* __restrict__ A, const bf16_t* __restrict__ B,
             void* __restrict__ Cv, int M, int N, int K, int nbn)
{
    __shared__ __align__(16) char lds[131072];

    const int nwg = gridDim.x;
    const int bid0 = blockIdx.x;
    const int bid = (bid0 & 7) * (nwg >> 3) + (bid0 >> 3);   // XCD swizzle
    const int bm = bid / nbn, bn = bid % nbn;
    const int t = threadIdx.x;
    const int lane = t & 63, wid = t >> 6;
    const int wm = wid >> 2, wn = wid & 3;          // 2M x 4N waves
    const int l15 = lane & 15, lg = lane >> 4;
    const int m0 = bm * 256, n0 = bn * 256;

    const int Krb = K * 2;
    const int srow = t >> 2;
    const int schunk = (((t & 3) ^ ((t >> 3) & 3)) << 4);    // pre-swizzled src
    const char* aS0 = (const char*)A + (size_t)(m0 + srow) * Krb + schunk;
    const char* aS1 = (const char*)A + (size_t)(m0 + 128 + srow) * Krb + schunk;
    const char* bS0 = (const char*)B + (size_t)(n0 + srow) * Krb + schunk;
    const char* bS1 = (const char*)B + (size_t)(n0 + 128 + srow) * Krb + schunk;
    char* sd = lds + t * 16;                                 // linear LDS dest

    const int rchunk = ((lg ^ ((l15 >> 1) & 3)) << 4);
    const unsigned ldsW = (unsigned)(size_t)lds;
    const unsigned aBase = ldsW + (unsigned)((wm * 128 + l15) * 64 + rchunk);
    const unsigned bBase = ldsW + (unsigned)(32768 + (wn * 64 + l15) * 64 + rchunk);

    const int NT = K >> 6;                                   // K-tiles of 64
    f32x4 acc[8][4] = {};
    f32x4 afX[4][2], afY[4][2], b0A[2][2], b0B[2][2], b1[2][2];

    // prologue: tile0 full + B(1); vmcnt(4) BEFORE barrier (publish), then
    // preread P1 frags after the barrier.
    SA(0, 0, 0); SA(0, 1, 0); SB(0, 0, 0); SB(0, 1, 0);
    SB(65536, 0, 128); SB(65536, 1, 128);
    asm volatile("s_waitcnt vmcnt(4)" ::: "memory"); SCB;
    BAR;
    LDA_ASM(afX, 0, 0); LDB_ASM(b0A, 0, 0);      // reads for P1 (tile 0)

    for (int T = 0; T < NT; T += 2) {
        const int k1 = (T + 1) * 128;                        // K-byte offsets
        const int k2 = (T + 2 < NT) ? (T + 2) * 128 : 0;
        const int k3 = (T + 3 < NT) ? (T + 3) * 128 : 0;
        // P1: MFMA Q(0,0) of T; reads for P2
        BAR;
        LDB_ASM(b1, 0, 1);
        SA(65536, 0, k1);
        WLGK("4");
        PRIO1; MMQ2(0, afX, b0A, 0); PRIO0; SCB;
        // P2: Q(0,1); reads for P3
        BAR;
        LDA_ASM(afY, 0, 1);
        SA(65536, 1, k1);
        WLGK("8");
        PRIO1; MMQ2(0, afX, b1, 2); PRIO0; SCB;
        // P3: Q(1,1); no reads; vmcnt(2) AFTER MFMA, BEFORE closing barrier
        // (publishes tile T+1: completes prevP7.SB,prevP8.SB,P1.SA,P2.SA)
        BAR;
        SB(0, 0, k2);
        WLGK("0");
        PRIO1; MMQ2(4, afY, b1, 2); PRIO0;
        WVM2;
        // P4: Q(1,0); reads for P5 (tile T+1, buf1) -- safe after BAR
        BAR;
        LDA_ASM(afX, 65536, 0); LDB_ASM(b0B, 65536, 0);
        SB(0, 1, k2);
        WLGK("12");
        PRIO1; MMQ2(4, afY, b0A, 0); PRIO0; SCB;
        // P5: Q(0,0) of T+1; reads for P6
        BAR;
        LDB_ASM(b1, 65536, 1);
        SA(0, 0, k2);
        WLGK("4");
        PRIO1; MMQ2(0, afX, b0B, 0); PRIO0; SCB;
        // P6: Q(0,1); reads for P7
        BAR;
        LDA_ASM(afY, 65536, 1);
        SA(0, 1, k2);
        WLGK("8");
        PRIO1; MMQ2(0, afX, b1, 2); PRIO0; SCB;
        // P7: Q(1,1); no reads; vmcnt(2) publishes tile T+2 before BAR_P8
        BAR;
        SB(65536, 0, k3);
        WLGK("0");
        PRIO1; MMQ2(4, afY, b1, 2); PRIO0;
        WVM2;
        // P8: Q(1,0); reads for next P1 (tile T+2, buf0)
        BAR;
        LDA_ASM(afX, 0, 0); LDB_ASM(b0A, 0, 0);
        SB(65536, 1, k3);
        WLGK("12");
        PRIO1; MMQ2(4, afY, b0B, 0); PRIO0; SCB;
    }

    // epilogue: D col = lane&15, row = (lane>>4)*4 + i
    #pragma unroll
    for (int m = 0; m < 8; ++m) {
        int row0 = m0 + wm * 128 + m * 16 + lg * 4;
        #pragma unroll
        for (int n = 0; n < 4; ++n) {
            int col = n0 + wn * 64 + n * 16 + l15;
            #pragma unroll
            for (int i = 0; i < 4; ++i) {
                if constexpr (OUT_F32)
                    ((float*)Cv)[(size_t)(row0 + i) * N + col] = acc[m][n][i];
                else
                    ((bf16_t*)Cv)[(size_t)(row0 + i) * N + col] = (bf16_t)acc[m][n][i];
            }
        }
    }
}

// ---------------------------------------------------------------------------
// 128x128 m97-structure GEMM for the KV projection (unchanged).
// ---------------------------------------------------------------------------
template<int MODE>
__global__ __launch_bounds__(256, 4)
void gemm_bt(const bf16_t* __restrict__ A, const bf16_t* __restrict__ B,
             void* __restrict__ Cv, bf16_t* __restrict__ Vt,
             int M, int N, int K, int nbn)
{
    __shared__ __align__(16) bf16_t lA[128 * 32];
    __shared__ __align__(16) bf16_t lB[128 * 32];

    const int nwg = gridDim.x;
    const int bid0 = blockIdx.x;
    const int bid = (bid0 & 7) * (nwg >> 3) + (bid0 >> 3);
    const int bm = bid / nbn, bn = bid % nbn;
    const int t = threadIdx.x;
    const int lane = t & 63, wid = t >> 6;
    const int wrow = (wid >> 1) * 64, wcol = (wid & 1) * 64;
    const int l15 = lane & 15, lg = lane >> 4;
    const int m0 = bm * 128, n0 = bn * 128;

    const int r0 = t >> 2, pos0 = (t & 3) * 8;
    const int r1 = r0 + 64;

    const bf16_t* Ar0 = A + (size_t)(m0 + r0) * K + pos0;
    const bf16_t* Ar1 = A + (size_t)(m0 + r1) * K + pos0;
    const bf16_t* Br0 = B + (size_t)(n0 + r0) * K + pos0;
    const bf16_t* Br1 = B + (size_t)(n0 + r1) * K + pos0;

    f32x4 acc[4][4] = {};

    for (int k0 = 0; k0 < K; k0 += 32) {
        __syncthreads();
        GLOAD_LDS16(Ar0 + k0, lA + t * 8);
        GLOAD_LDS16(Ar1 + k0, lA + (t + 256) * 8);
        GLOAD_LDS16(Br0 + k0, lB + t * 8);
        GLOAD_LDS16(Br1 + k0, lB + (t + 256) * 8);
        __syncthreads();

        bf16x8 af[4], bfr[4];
        #pragma unroll
        for (int m = 0; m < 4; ++m)
            af[m] = *(const bf16x8*)(lA + (wrow + m * 16 + l15) * 32 + lg * 8);
        #pragma unroll
        for (int n = 0; n < 4; ++n)
            bfr[n] = *(const bf16x8*)(lB + (wcol + n * 16 + l15) * 32 + lg * 8);
        #pragma unroll
        for (int m = 0; m < 4; ++m)
            #pragma unroll
            for (int n = 0; n < 4; ++n)
                acc[m][n] = __builtin_amdgcn_mfma_f32_16x16x32_bf16(
                    af[m], bfr[n], acc[m][n], 0, 0, 0);
    }

    #pragma unroll
    for (int m = 0; m < 4; ++m) {
        #pragma unroll
        for (int n = 0; n < 4; ++n) {
            int col  = n0 + wcol + n * 16 + l15;
            int row0 = m0 + wrow + m * 16 + lg * 4;
            if constexpr (MODE == 0) {
                #pragma unroll
                for (int i = 0; i < 4; ++i)
                    ((bf16_t*)Cv)[(size_t)(row0 + i) * N + col] = (bf16_t)acc[m][n][i];
            } else if constexpr (MODE == 1) {
                #pragma unroll
                for (int i = 0; i < 4; ++i)
                    ((float*)Cv)[(size_t)(row0 + i) * N + col] = acc[m][n][i];
            } else {
                if (col < 1024) {
                    #pragma unroll
                    for (int i = 0; i < 4; ++i)
                        ((bf16_t*)Cv)[(size_t)(row0 + i) * 1024 + col] = (bf16_t)acc[m][n][i];
                } else {
                    bf16x4 pk;
                    #pragma unroll
                    for (int i = 0; i < 4; ++i) pk[i] = (bf16_t)acc[m][n][i];
                    *(bf16x4*)(Vt + (size_t)(col - 1024) * 4096 + row0) = pk;
                }
            }
        }
    }
}

// ---------------------------------------------------------------------------
// RoPE (interleaved pairs), in-place on bf16, 8 elems (4 pairs) per thread.
// oscale folds attention's 1/sqrt(HD)*log2(e) into Q.
// ---------------------------------------------------------------------------
__global__ __launch_bounds__(256)
void rope_kernel(bf16_t* __restrict__ X, const float* __restrict__ fc,
                 const float* __restrict__ fs, int nheads, int rowstride,
                 float oscale)
{
    int idx = blockIdx.x * 256 + threadIdx.x;
    int j4 = idx & 15;
    int rest = idx >> 4;
    int h = rest % nheads;
    int tok = rest / nheads;
    int s = tok & (SEQ - 1);
    bf16_t* p = X + (size_t)tok * rowstride + h * HDIM + j4 * 8;
    bf16x8 v = *(const bf16x8*)p;
    float4 c  = *(const float4*)(fc + s * 64 + j4 * 4);
    float4 sn = *(const float4*)(fs + s * 64 + j4 * 4);
    c.x *= oscale; c.y *= oscale; c.z *= oscale; c.w *= oscale;
    sn.x *= oscale; sn.y *= oscale; sn.z *= oscale; sn.w *= oscale;
    bf16x8 o;
    o[0] = (bf16_t)((float)v[0] * c.x - (float)v[1] * sn.x);
    o[1] = (bf16_t)((float)v[0] * sn.x + (float)v[1] * c.x);
    o[2] = (bf16_t)((float)v[2] * c.y - (float)v[3] * sn.y);
    o[3] = (bf16_t)((float)v[2] * sn.y + (float)v[3] * c.y);
    o[4] = (bf16_t)((float)v[4] * c.z - (float)v[5] * sn.z);
    o[5] = (bf16_t)((float)v[4] * sn.z + (float)v[5] * c.z);
    o[6] = (bf16_t)((float)v[6] * c.w - (float)v[7] * sn.w);
    o[7] = (bf16_t)((float)v[6] * sn.w + (float)v[7] * c.w);
    *(bf16x8*)p = o;
}

// ---------------------------------------------------------------------------
// Flash attention (round-11, unchanged/passing): fixed-shift softmax
// (exp2(s'-20)), per-lane l accumulation, PV on 16x16x32 MFMA via permuted
// K-row map + cvt_pk + shfl_xor(16) A-frag assembly, double-buffered KV.
// ---------------------------------------------------------------------------
__global__ __launch_bounds__(512, 2)
void attn_kernel(const bf16_t* __restrict__ Q, const bf16_t* __restrict__ Kg,
                 const bf16_t* __restrict__ Vtg, bf16_t* __restrict__ O)
{
    __shared__ __align__(16) char klds[2][64 * 256];    // K tiles, swizzled+row-permuted
    __shared__ __align__(16) char vlds[2][128 * 128];   // V^T tiles, swizzled

    const int nwg = gridDim.x;
    const int bid0 = blockIdx.x;
    const int blk = (bid0 & 7) * (nwg >> 3) + (bid0 >> 3);   // XCD swizzle
    const int qt = blk & 7;            // q-tile of 128 rows
    const int bh = blk >> 3;           // 0..127
    const int b = bh >> 5, h = bh & 31, kv = h >> 2;
    const int t = threadIdx.x, lane = t & 63, wid = t >> 6;  // wid 0..7
    const int l15 = lane & 15, lg = lane >> 4;
    const int swzk = (l15 & 7) << 4;

    const int qrow = qt * 128 + wid * 16 + l15;
    const size_t qbase = (size_t)(b * SEQ + qrow) * DMODEL + h * HDIM;
    bf16x8 qf[4];
    #pragma unroll
    for (int dc = 0; dc < 4; ++dc)
        qf[dc] = *(const bf16x8*)(Q + qbase + dc * 32 + lg * 8);

    const char* kgb = (const char*)Kg + ((size_t)(b * SEQ) * 1024 + kv * HDIM) * 2;
    const char* vgb = (const char*)Vtg + ((size_t)(kv * HDIM) * 4096 + b * SEQ) * 2;

    const int ck0 = t, ck1 = t + 512;
    const int kr0 = ck0 >> 4, kr1 = ck1 >> 4;
    const int kg0 = ((kr0 >> 5) << 5) + (((((kr0 & 15) >> 2) ^ ((kr0 >> 4) & 1)) << 3))
                  + (((kr0 >> 4) & 1) << 2) + (kr0 & 3);
    const int kg1 = ((kr1 >> 5) << 5) + (((((kr1 & 15) >> 2) ^ ((kr1 >> 4) & 1)) << 3))
                  + (((kr1 >> 4) & 1) << 2) + (kr1 & 3);
    const int kf0 = kg0 * 2048 + ((((ck0 & 15) << 4)) ^ ((kr0 & 7) << 4));
    const int kf1 = kg1 * 2048 + ((((ck1 & 15) << 4)) ^ ((kr1 & 7) << 4));
    const int vd0 = ck0 >> 3, vf0 = vd0 * 8192 + ((((ck0 & 7) << 4)) ^ ((vd0 & 7) << 4));
    const int vd1 = ck1 >> 3, vf1 = vd1 * 8192 + ((((ck1 & 7) << 4)) ^ ((vd1 & 7) << 4));

    f32x4 o[8] = {};
    float lrun = 0.f;

#define STAGE_KV(kt_, bi_) do {                                            \
    GLOAD_LDS16(kgb + (size_t)(kt_) * 131072 + kf0, klds[bi_] + ck0 * 16); \
    GLOAD_LDS16(kgb + (size_t)(kt_) * 131072 + kf1, klds[bi_] + ck1 * 16); \
    GLOAD_LDS16(vgb + (kt_) * 128 + vf0, vlds[bi_] + ck0 * 16);            \
    GLOAD_LDS16(vgb + (kt_) * 128 + vf1, vlds[bi_] + ck1 * 16);            \
} while (0)

    STAGE_KV(0, 0);
    __syncthreads();

    for (int kt = 0; kt < 16; ++kt) {
        const int cur = kt & 1;
        const int knx = (kt + 1 < 16) ? kt + 1 : 15;
        STAGE_KV(knx, cur ^ 1);                  // prefetch under compute

        f32x4 sacc[4] = {};
        #pragma unroll
        for (int kb = 0; kb < 4; ++kb) {
            const char* krow = klds[cur] + (kb * 16 + l15) * 256;
            #pragma unroll
            for (int dc = 0; dc < 4; ++dc) {
                bf16x8 kf = *(const bf16x8*)(krow + ((dc * 64 + lg * 16) ^ swzk));
                sacc[kb] = __builtin_amdgcn_mfma_f32_16x16x32_bf16(
                    kf, qf[dc], sacc[kb], 0, 0, 0);
            }
        }

        float ts = 0.f;
        unsigned qpk[4][2];
        #pragma unroll
        for (int kb = 0; kb < 4; ++kb) {
            float p0 = exp2f(sacc[kb][0] - 20.0f);
            float p1 = exp2f(sacc[kb][1] - 20.0f);
            float p2 = exp2f(sacc[kb][2] - 20.0f);
            float p3 = exp2f(sacc[kb][3] - 20.0f);
            ts += (p0 + p1) + (p2 + p3);
            asm("v_cvt_pk_bf16_f32 %0, %1, %2" : "=v"(qpk[kb][0]) : "v"(p0), "v"(p1));
            asm("v_cvt_pk_bf16_f32 %0, %1, %2" : "=v"(qpk[kb][1]) : "v"(p2), "v"(p3));
        }
        lrun += ts;

        #pragma unroll
        for (int c = 0; c < 2; ++c) {
            unsigned s0 = (unsigned)__shfl_xor((int)qpk[2 * c + 1][0], 16);
            unsigned s1 = (unsigned)__shfl_xor((int)qpk[2 * c + 1][1], 16);
            u32x4 w;
            w[0] = qpk[2 * c][0]; w[1] = qpk[2 * c][1]; w[2] = s0; w[3] = s1;
            bf16x8 a32 = __builtin_bit_cast(bf16x8, w);
            #pragma unroll
            for (int db = 0; db < 8; ++db) {
                int d = l15 + 16 * db;
                const char* va = vlds[cur] + d * 128 + ((c * 64 + lg * 16) ^ swzk);
                bf16x8 vf = *(const bf16x8*)va;
                o[db] = __builtin_amdgcn_mfma_f32_16x16x32_bf16(
                    a32, vf, o[db], 0, 0, 0);
            }
        }

        __syncthreads();
    }
#undef STAGE_KV

    lrun += __shfl_xor(lrun, 16);
    lrun += __shfl_xor(lrun, 32);

    #pragma unroll
    for (int i = 0; i < 4; ++i) {
        float li = __shfl(lrun, lg * 4 + i);
        float inv = 1.0f / li;
        int row = b * SEQ + qt * 128 + wid * 16 + lg * 4 + i;
        #pragma unroll
        for (int db = 0; db < 8; ++db) {
            int col = h * HDIM + l15 + 16 * db;
            O[(size_t)row * DMODEL + col] = (bf16_t)(o[db][i] * inv);
        }
    }
}

// ---------------------------------------------------------------------------
// Launch. Workspace (bf16): Qw 32M | Kw2 8M | Vt 8M | AO 32M | xb 32M |
// wqb 32M | wkvb 16M | wob 32M = 192 MiB.
// ---------------------------------------------------------------------------
extern "C" void kernel_launch(void* const* d_in, const int* in_sizes, int n_in,
                              void* d_out, int out_size, void* d_ws, size_t ws_size,
                              hipStream_t stream)
{
    const float* x  = (const float*)d_in[0];
    const float* wq = (const float*)d_in[1];
    const float* wk = (const float*)d_in[2];
    const float* wv = (const float*)d_in[3];
    const float* wo = (const float*)d_in[4];
    const float* fc = (const float*)d_in[5];
    const float* fs = (const float*)d_in[6];

    const size_t T = (size_t)4096;
    bf16_t* Qw   = (bf16_t*)d_ws;            // [4096][4096]
    bf16_t* Kw2  = Qw   + T * 4096;          // [4096][1024]
    bf16_t* Vt   = Kw2  + T * 1024;          // [1024(kv*128+d)][4096 tok]
    bf16_t* AO   = Vt   + T * 1024;          // [4096][4096]
    bf16_t* xb   = AO   + T * 4096;          // [4096][4096]
    bf16_t* wqb  = xb   + T * 4096;          // [4096][4096]
    bf16_t* wkvb = wqb  + T * 4096;          // [2048][4096]  (wk ; wv)
    bf16_t* wob  = wkvb + T * 2048;          // [4096][4096]

    f2b<<<8192, 256, 0, stream>>>(x,  xb,  4096 * 4096 / 8);
    f2b<<<8192, 256, 0, stream>>>(wq, wqb, 4096 * 4096 / 8);
    f2b<<<2048, 256, 0, stream>>>(wk, wkvb,                       1024 * 4096 / 8);
    f2b<<<2048, 256, 0, stream>>>(wv, wkvb + (size_t)1024 * 4096, 1024 * 4096 / 8);
    f2b<<<8192, 256, 0, stream>>>(wo, wob, 4096 * 4096 / 8);

    gemm256<false><<<256, 512, 0, stream>>>(xb, wqb, Qw, 4096, 4096, 4096, 16);
    gemm_bt<2><<<512, 256, 0, stream>>>(xb, wkvb, Kw2, Vt, 4096, 2048, 4096, 16);

    // Q prescale = (1/sqrt(128)) * log2(e): softmax becomes pure exp2
    rope_kernel<<<8192, 256, 0, stream>>>(Qw,  fc, fs, NHQ,  4096,
                                          0.08838834764831845f * 1.4426950408889634f);
    rope_kernel<<<2048, 256, 0, stream>>>(Kw2, fc, fs, NHKV, 1024, 1.0f);

    attn_kernel<<<1024, 512, 0, stream>>>(Qw, Kw2, Vt, AO);

    gemm256<true><<<256, 512, 0, stream>>>(AO, wob, d_out, 4096, 4096, 4096, 16);
}

// Round 15
// 486.912 us; speedup vs baseline: 1.0170x; 1.0170x over previous
//
#include <hip/hip_runtime.h>

typedef __bf16 bf16_t;
typedef __bf16 bf16x8 __attribute__((ext_vector_type(8)));
typedef __bf16 bf16x4 __attribute__((ext_vector_type(4)));
typedef float  f32x4  __attribute__((ext_vector_type(4)));
typedef unsigned u32x4 __attribute__((ext_vector_type(4)));

#define SEQ    1024
#define DMODEL 4096
#define NHQ    32
#define NHKV   8
#define HDIM   128

// async global->LDS, 16B per lane; LDS dest must be linear (base + lane*16)
#define GLOAD_LDS16(g, l)                                                  \
    __builtin_amdgcn_global_load_lds(                                      \
        (const __attribute__((address_space(1))) unsigned int*)(g),        \
        (__attribute__((address_space(3))) unsigned int*)(l), 16, 0, 0)

// ---------------------------------------------------------------------------
// fp32 -> bf16 convert, 8 elems/thread
// ---------------------------------------------------------------------------
__global__ __launch_bounds__(256)
void f2b(const float* __restrict__ in, bf16_t* __restrict__ out, int n8)
{
    int i = blockIdx.x * 256 + threadIdx.x;
    if (i >= n8) return;
    const float4* p = (const float4*)in + 2 * (size_t)i;
    float4 a = p[0], b = p[1];
    bf16x8 o;
    o[0] = (bf16_t)a.x; o[1] = (bf16_t)a.y; o[2] = (bf16_t)a.z; o[3] = (bf16_t)a.w;
    o[4] = (bf16_t)b.x; o[5] = (bf16_t)b.y; o[6] = (bf16_t)b.z; o[7] = (bf16_t)b.w;
    *((bf16x8*)out + i) = o;
}

// ---------------------------------------------------------------------------
// 256x256 8-wave GEMM -- ROUND-11 VERSION (best known: 119 us, MfmaUtil 50%,
// 0 conflicts). 8-phase, BK=64, dbuf over even/odd K-tiles, compiler-
// scheduled ds_reads, raw s_barriers, setprio, counted vmcnt(4) at P4/P8
// BEFORE the closing barrier (per-wave certify, barrier publishes).
// ---------------------------------------------------------------------------
#define MFMA_(a, b, c) __builtin_amdgcn_mfma_f32_16x16x32_bf16(a, b, c, 0, 0, 0)
#define BAR    __builtin_amdgcn_s_barrier()
#define SCB    __builtin_amdgcn_sched_barrier(0)
#define PRIO1  __builtin_amdgcn_s_setprio(1)
#define PRIO0  __builtin_amdgcn_s_setprio(0)
#define WVM4   do { asm volatile("s_waitcnt vmcnt(4)" ::: "memory"); SCB; } while (0)

#define SA(bufo, half, ktb)  do {                                          \
    const char* g_ = ((half) ? aS1 : aS0) + (ktb);                         \
    GLOAD_LDS16(g_,      sd + (bufo) + (half) * 8192);                     \
    GLOAD_LDS16(g_ + 64, sd + (bufo) + (half) * 8192 + 16384);             \
} while (0)
#define SB(bufo, half, ktb)  do {                                          \
    const char* g_ = ((half) ? bS1 : bS0) + (ktb);                         \
    GLOAD_LDS16(g_,      sd + (bufo) + 32768 + (half) * 8192);             \
    GLOAD_LDS16(g_ + 64, sd + (bufo) + 32768 + (half) * 8192 + 16384);     \
} while (0)
#define LDA(bufo, mh) do { _Pragma("unroll")                               \
    for (int j = 0; j < 4; ++j) {                                          \
        afq[j][0] = *(const bf16x8*)(lds + (bufo) + aRow + (mh)*4096 + j*1024);         \
        afq[j][1] = *(const bf16x8*)(lds + (bufo) + aRow + (mh)*4096 + j*1024 + 16384); \
    } } while (0)
#define LDB(bufo, nh, dst) do { _Pragma("unroll")                          \
    for (int n2 = 0; n2 < 2; ++n2) {                                       \
        dst[n2][0] = *(const bf16x8*)(lds + (bufo) + bRow + (nh)*2048 + n2*1024);         \
        dst[n2][1] = *(const bf16x8*)(lds + (bufo) + bRow + (nh)*2048 + n2*1024 + 16384); \
    } } while (0)
#define MMQ(mlo, bfx, nlo) do { _Pragma("unroll")                          \
    for (int j = 0; j < 4; ++j) {                                          \
        acc[(mlo)+j][(nlo)  ] = MFMA_(afq[j][0], bfx[0][0], acc[(mlo)+j][(nlo)  ]); \
        acc[(mlo)+j][(nlo)  ] = MFMA_(afq[j][1], bfx[0][1], acc[(mlo)+j][(nlo)  ]); \
        acc[(mlo)+j][(nlo)+1] = MFMA_(afq[j][0], bfx[1][0], acc[(mlo)+j][(nlo)+1]); \
        acc[(mlo)+j][(nlo)+1] = MFMA_(afq[j][1], bfx[1][1], acc[(mlo)+j][(nlo)+1]); \
    } } while (0)

template<bool OUT_F32>
__global__ __launch_bounds__(512, 2)
void gemm256(const bf16_t* __restrict__ A, const bf16_t* __restrict__ B,
             void* __restrict__ Cv, int M, int N, int K, int nbn)
{
    __shared__ __align__(16) char lds[131072];

    const int nwg = gridDim.x;
    const int bid0 = blockIdx.x;
    const int bid = (bid0 & 7) * (nwg >> 3) + (bid0 >> 3);   // XCD swizzle
    const int bm = bid / nbn, bn = bid % nbn;
    const int t = threadIdx.x;
    const int lane = t & 63, wid = t >> 6;
    const int wm = wid >> 2, wn = wid & 3;          // 2M x 4N waves
    const int l15 = lane & 15, lg = lane >> 4;
    const int m0 = bm * 256, n0 = bn * 256;

    const int Krb = K * 2;
    const int srow = t >> 2;
    const int schunk = (((t & 3) ^ ((t >> 3) & 3)) << 4);    // pre-swizzled src
    const char* aS0 = (const char*)A + (size_t)(m0 + srow) * Krb + schunk;
    const char* aS1 = (const char*)A + (size_t)(m0 + 128 + srow) * Krb + schunk;
    const char* bS0 = (const char*)B + (size_t)(n0 + srow) * Krb + schunk;
    const char* bS1 = (const char*)B + (size_t)(n0 + 128 + srow) * Krb + schunk;
    char* sd = lds + t * 16;                                 // linear LDS dest

    const int rchunk = ((lg ^ ((l15 >> 1) & 3)) << 4);
    const int aRow = (wm * 128 + l15) * 64 + rchunk;
    const int bRow = 32768 + (wn * 64 + l15) * 64 + rchunk;

    const int NT = K >> 6;                                   // K-tiles of 64
    f32x4 acc[8][4] = {};
    bf16x8 afq[4][2], bf0[2][2], bf1[2][2];

    SA(0, 0, 0); SA(0, 1, 0); SB(0, 0, 0); SB(0, 1, 0);
    SB(65536, 0, 128); SB(65536, 1, 128);
    WVM4;
    BAR;

    for (int T = 0; T < NT; T += 2) {
        const int k1 = (T + 1) * 128;                        // K-byte offsets
        const int k2 = (T + 2 < NT) ? (T + 2) * 128 : 0;
        const int k3 = (T + 3 < NT) ? (T + 3) * 128 : 0;
        // P1: Q(0,0) of T (buf0)
        LDA(0, 0); LDB(0, 0, bf0); SA(65536, 0, k1); BAR; SCB;
        PRIO1; MMQ(0, bf0, 0); PRIO0; BAR;
        // P2: Q(0,1)
        LDB(0, 1, bf1); SA(65536, 1, k1); BAR; SCB;
        PRIO1; MMQ(0, bf1, 2); PRIO0; BAR;
        // P3: Q(1,1)
        LDA(0, 1); SB(0, 0, k2); BAR; SCB;
        PRIO1; MMQ(4, bf1, 2); PRIO0; BAR;
        // P4: Q(1,0)  (no reads)
        SB(0, 1, k2); BAR;
        PRIO1; MMQ(4, bf0, 0); PRIO0; WVM4; BAR;
        // P5: Q(0,0) of T+1 (buf1)
        LDA(65536, 0); LDB(65536, 0, bf0); SA(0, 0, k2); BAR; SCB;
        PRIO1; MMQ(0, bf0, 0); PRIO0; BAR;
        // P6: Q(0,1)
        LDB(65536, 1, bf1); SA(0, 1, k2); BAR; SCB;
        PRIO1; MMQ(0, bf1, 2); PRIO0; BAR;
        // P7: Q(1,1)
        LDA(65536, 1); SB(65536, 0, k3); BAR; SCB;
        PRIO1; MMQ(4, bf1, 2); PRIO0; BAR;
        // P8: Q(1,0)
        SB(65536, 1, k3); BAR;
        PRIO1; MMQ(4, bf0, 0); PRIO0; WVM4; BAR;
    }

    #pragma unroll
    for (int m = 0; m < 8; ++m) {
        int row0 = m0 + wm * 128 + m * 16 + lg * 4;
        #pragma unroll
        for (int n = 0; n < 4; ++n) {
            int col = n0 + wn * 64 + n * 16 + l15;
            #pragma unroll
            for (int i = 0; i < 4; ++i) {
                if constexpr (OUT_F32)
                    ((float*)Cv)[(size_t)(row0 + i) * N + col] = acc[m][n][i];
                else
                    ((bf16_t*)Cv)[(size_t)(row0 + i) * N + col] = (bf16_t)acc[m][n][i];
            }
        }
    }
}

// ---------------------------------------------------------------------------
// 128x128 m97-structure GEMM for the KV projection (unchanged).
// ---------------------------------------------------------------------------
template<int MODE>
__global__ __launch_bounds__(256, 4)
void gemm_bt(const bf16_t* __restrict__ A, const bf16_t* __restrict__ B,
             void* __restrict__ Cv, bf16_t* __restrict__ Vt,
             int M, int N, int K, int nbn)
{
    __shared__ __align__(16) bf16_t lA[128 * 32];
    __shared__ __align__(16) bf16_t lB[128 * 32];

    const int nwg = gridDim.x;
    const int bid0 = blockIdx.x;
    const int bid = (bid0 & 7) * (nwg >> 3) + (bid0 >> 3);
    const int bm = bid / nbn, bn = bid % nbn;
    const int t = threadIdx.x;
    const int lane = t & 63, wid = t >> 6;
    const int wrow = (wid >> 1) * 64, wcol = (wid & 1) * 64;
    const int l15 = lane & 15, lg = lane >> 4;
    const int m0 = bm * 128, n0 = bn * 128;

    const int r0 = t >> 2, pos0 = (t & 3) * 8;
    const int r1 = r0 + 64;

    const bf16_t* Ar0 = A + (size_t)(m0 + r0) * K + pos0;
    const bf16_t* Ar1 = A + (size_t)(m0 + r1) * K + pos0;
    const bf16_t* Br0 = B + (size_t)(n0 + r0) * K + pos0;
    const bf16_t* Br1 = B + (size_t)(n0 + r1) * K + pos0;

    f32x4 acc[4][4] = {};

    for (int k0 = 0; k0 < K; k0 += 32) {
        __syncthreads();
        GLOAD_LDS16(Ar0 + k0, lA + t * 8);
        GLOAD_LDS16(Ar1 + k0, lA + (t + 256) * 8);
        GLOAD_LDS16(Br0 + k0, lB + t * 8);
        GLOAD_LDS16(Br1 + k0, lB + (t + 256) * 8);
        __syncthreads();

        bf16x8 af[4], bfr[4];
        #pragma unroll
        for (int m = 0; m < 4; ++m)
            af[m] = *(const bf16x8*)(lA + (wrow + m * 16 + l15) * 32 + lg * 8);
        #pragma unroll
        for (int n = 0; n < 4; ++n)
            bfr[n] = *(const bf16x8*)(lB + (wcol + n * 16 + l15) * 32 + lg * 8);
        #pragma unroll
        for (int m = 0; m < 4; ++m)
            #pragma unroll
            for (int n = 0; n < 4; ++n)
                acc[m][n] = __builtin_amdgcn_mfma_f32_16x16x32_bf16(
                    af[m], bfr[n], acc[m][n], 0, 0, 0);
    }

    #pragma unroll
    for (int m = 0; m < 4; ++m) {
        #pragma unroll
        for (int n = 0; n < 4; ++n) {
            int col  = n0 + wcol + n * 16 + l15;
            int row0 = m0 + wrow + m * 16 + lg * 4;
            if constexpr (MODE == 0) {
                #pragma unroll
                for (int i = 0; i < 4; ++i)
                    ((bf16_t*)Cv)[(size_t)(row0 + i) * N + col] = (bf16_t)acc[m][n][i];
            } else if constexpr (MODE == 1) {
                #pragma unroll
                for (int i = 0; i < 4; ++i)
                    ((float*)Cv)[(size_t)(row0 + i) * N + col] = acc[m][n][i];
            } else {
                if (col < 1024) {
                    #pragma unroll
                    for (int i = 0; i < 4; ++i)
                        ((bf16_t*)Cv)[(size_t)(row0 + i) * 1024 + col] = (bf16_t)acc[m][n][i];
                } else {
                    bf16x4 pk;
                    #pragma unroll
                    for (int i = 0; i < 4; ++i) pk[i] = (bf16_t)acc[m][n][i];
                    *(bf16x4*)(Vt + (size_t)(col - 1024) * 4096 + row0) = pk;
                }
            }
        }
    }
}

// ---------------------------------------------------------------------------
// RoPE (interleaved pairs), in-place on bf16, 8 elems (4 pairs) per thread.
// oscale folds attention's 1/sqrt(HD)*log2(e) into Q.
// ---------------------------------------------------------------------------
__global__ __launch_bounds__(256)
void rope_kernel(bf16_t* __restrict__ X, const float* __restrict__ fc,
                 const float* __restrict__ fs, int nheads, int rowstride,
                 float oscale)
{
    int idx = blockIdx.x * 256 + threadIdx.x;
    int j4 = idx & 15;
    int rest = idx >> 4;
    int h = rest % nheads;
    int tok = rest / nheads;
    int s = tok & (SEQ - 1);
    bf16_t* p = X + (size_t)tok * rowstride + h * HDIM + j4 * 8;
    bf16x8 v = *(const bf16x8*)p;
    float4 c  = *(const float4*)(fc + s * 64 + j4 * 4);
    float4 sn = *(const float4*)(fs + s * 64 + j4 * 4);
    c.x *= oscale; c.y *= oscale; c.z *= oscale; c.w *= oscale;
    sn.x *= oscale; sn.y *= oscale; sn.z *= oscale; sn.w *= oscale;
    bf16x8 o;
    o[0] = (bf16_t)((float)v[0] * c.x - (float)v[1] * sn.x);
    o[1] = (bf16_t)((float)v[0] * sn.x + (float)v[1] * c.x);
    o[2] = (bf16_t)((float)v[2] * c.y - (float)v[3] * sn.y);
    o[3] = (bf16_t)((float)v[2] * sn.y + (float)v[3] * c.y);
    o[4] = (bf16_t)((float)v[4] * c.z - (float)v[5] * sn.z);
    o[5] = (bf16_t)((float)v[4] * sn.z + (float)v[5] * c.z);
    o[6] = (bf16_t)((float)v[6] * c.w - (float)v[7] * sn.w);
    o[7] = (bf16_t)((float)v[6] * sn.w + (float)v[7] * c.w);
    *(bf16x8*)p = o;
}

// ---------------------------------------------------------------------------
// Flash attention (non-causal), GQA 4:1. Q pre-scaled by log2(e)/sqrt(HD).
// Round-15: r11 sync skeleton (STAGE -> compute -> __syncthreads, depth-1
// dbuf -- the PROVEN-safe structure) with QBLK=256: each wave owns TWO
// 16-row q-groups (rows +0 and +128). Every K/V LDS read now feeds 2 MFMAs
// -> LDS read traffic per FLOP halves (attn was ~3x LDS-bw-bound: 8 waves
// x 32 b128/iter = 262KB/block-iter vs 1024cy MFMA). Staging, swizzles,
// K-row permutation, fixed-shift softmax all unchanged from r11.
// Grid 512 blocks (4 q-tiles x 128 bh), 2 blocks/CU, 64KB LDS.
// ---------------------------------------------------------------------------
__global__ __launch_bounds__(512, 2)
void attn_kernel(const bf16_t* __restrict__ Q, const bf16_t* __restrict__ Kg,
                 const bf16_t* __restrict__ Vtg, bf16_t* __restrict__ O)
{
    __shared__ __align__(16) char klds[2][16384];    // K tiles, swizzled+row-permuted
    __shared__ __align__(16) char vlds[2][16384];    // V^T tiles, swizzled

    const int nwg = gridDim.x;
    const int bid0 = blockIdx.x;
    const int blk = (bid0 & 7) * (nwg >> 3) + (bid0 >> 3);   // XCD swizzle
    const int qt = blk & 3;            // q-tile of 256 rows
    const int bh = blk >> 2;           // 0..127
    const int b = bh >> 5, h = bh & 31, kv = h >> 2;
    const int t = threadIdx.x, lane = t & 63, wid = t >> 6;  // wid 0..7
    const int l15 = lane & 15, lg = lane >> 4;
    const int swzk = (l15 & 7) << 4;

    // two q-groups per wave: rows qa (+0) and qb (+128) within the 256-tile
    const int qrowa = qt * 256 + wid * 16 + l15;
    const size_t qbasea = (size_t)(b * SEQ + qrowa) * DMODEL + h * HDIM;
    const size_t qbaseb = qbasea + (size_t)128 * DMODEL;
    bf16x8 qfa[4], qfb[4];
    #pragma unroll
    for (int dc = 0; dc < 4; ++dc) {
        qfa[dc] = *(const bf16x8*)(Q + qbasea + dc * 32 + lg * 8);
        qfb[dc] = *(const bf16x8*)(Q + qbaseb + dc * 32 + lg * 8);
    }

    const char* kgb = (const char*)Kg + ((size_t)(b * SEQ) * 1024 + kv * HDIM) * 2;
    const char* vgb = (const char*)Vtg + ((size_t)(kv * HDIM) * 4096 + b * SEQ) * 2;

    // staging: 1024 K-chunks + 1024 V-chunks of 16B; thread t takes chunks
    // {t, t+512}. K rows permuted (g(r)) for the PV K=32 A-frag layout.
    const int ck0 = t, ck1 = t + 512;
    const int kr0 = ck0 >> 4, kr1 = ck1 >> 4;
    const int kg0 = ((kr0 >> 5) << 5) + (((((kr0 & 15) >> 2) ^ ((kr0 >> 4) & 1)) << 3))
                  + (((kr0 >> 4) & 1) << 2) + (kr0 & 3);
    const int kg1 = ((kr1 >> 5) << 5) + (((((kr1 & 15) >> 2) ^ ((kr1 >> 4) & 1)) << 3))
                  + (((kr1 >> 4) & 1) << 2) + (kr1 & 3);
    const int kf0 = kg0 * 2048 + ((((ck0 & 15) << 4)) ^ ((kr0 & 7) << 4));
    const int kf1 = kg1 * 2048 + ((((ck1 & 15) << 4)) ^ ((kr1 & 7) << 4));
    const int vd0 = ck0 >> 3, vf0 = vd0 * 8192 + ((((ck0 & 7) << 4)) ^ ((vd0 & 7) << 4));
    const int vd1 = ck1 >> 3, vf1 = vd1 * 8192 + ((((ck1 & 7) << 4)) ^ ((vd1 & 7) << 4));

    f32x4 oa[8] = {}, ob[8] = {};
    float lruna = 0.f, lrunb = 0.f;

#define STAGE_KV(kt_, bi_) do {                                            \
    GLOAD_LDS16(kgb + (size_t)(kt_) * 131072 + kf0, klds[bi_] + ck0 * 16); \
    GLOAD_LDS16(kgb + (size_t)(kt_) * 131072 + kf1, klds[bi_] + ck1 * 16); \
    GLOAD_LDS16(vgb + (kt_) * 128 + vf0, vlds[bi_] + ck0 * 16);            \
    GLOAD_LDS16(vgb + (kt_) * 128 + vf1, vlds[bi_] + ck1 * 16);            \
} while (0)

    STAGE_KV(0, 0);
    __syncthreads();

    for (int kt = 0; kt < 16; ++kt) {
        const int cur = kt & 1;
        const int knx = (kt + 1 < 16) ? kt + 1 : 15;
        STAGE_KV(knx, cur ^ 1);                  // prefetch under compute

        f32x4 sacca[4] = {}, saccb[4] = {};
        #pragma unroll
        for (int kb = 0; kb < 4; ++kb) {
            const char* krow = klds[cur] + (kb * 16 + l15) * 256;
            #pragma unroll
            for (int dc = 0; dc < 4; ++dc) {
                bf16x8 kf = *(const bf16x8*)(krow + ((dc * 64 + lg * 16) ^ swzk));
                sacca[kb] = __builtin_amdgcn_mfma_f32_16x16x32_bf16(
                    kf, qfa[dc], sacca[kb], 0, 0, 0);
                saccb[kb] = __builtin_amdgcn_mfma_f32_16x16x32_bf16(
                    kf, qfb[dc], saccb[kb], 0, 0, 0);
            }
        }

        // fixed-shift softmax: P = exp2(s' - 20), no max, no rescale
        float tsa = 0.f, tsb = 0.f;
        unsigned qpka[4][2], qpkb[4][2];
        #pragma unroll
        for (int kb = 0; kb < 4; ++kb) {
            float a0 = exp2f(sacca[kb][0] - 20.0f);
            float a1 = exp2f(sacca[kb][1] - 20.0f);
            float a2 = exp2f(sacca[kb][2] - 20.0f);
            float a3 = exp2f(sacca[kb][3] - 20.0f);
            tsa += (a0 + a1) + (a2 + a3);
            asm("v_cvt_pk_bf16_f32 %0, %1, %2" : "=v"(qpka[kb][0]) : "v"(a0), "v"(a1));
            asm("v_cvt_pk_bf16_f32 %0, %1, %2" : "=v"(qpka[kb][1]) : "v"(a2), "v"(a3));
            float b0 = exp2f(saccb[kb][0] - 20.0f);
            float b1 = exp2f(saccb[kb][1] - 20.0f);
            float b2 = exp2f(saccb[kb][2] - 20.0f);
            float b3 = exp2f(saccb[kb][3] - 20.0f);
            tsb += (b0 + b1) + (b2 + b3);
            asm("v_cvt_pk_bf16_f32 %0, %1, %2" : "=v"(qpkb[kb][0]) : "v"(b0), "v"(b1));
            asm("v_cvt_pk_bf16_f32 %0, %1, %2" : "=v"(qpkb[kb][1]) : "v"(b2), "v"(b3));
        }
        lruna += tsa;
        lrunb += tsb;

        // PV: two K=32 MFMAs per d-block per group; each vf read feeds both
        #pragma unroll
        for (int c = 0; c < 2; ++c) {
            unsigned sa0 = (unsigned)__shfl_xor((int)qpka[2 * c + 1][0], 16);
            unsigned sa1 = (unsigned)__shfl_xor((int)qpka[2 * c + 1][1], 16);
            unsigned sb0 = (unsigned)__shfl_xor((int)qpkb[2 * c + 1][0], 16);
            unsigned sb1 = (unsigned)__shfl_xor((int)qpkb[2 * c + 1][1], 16);
            u32x4 wa, wb;
            wa[0] = qpka[2 * c][0]; wa[1] = qpka[2 * c][1]; wa[2] = sa0; wa[3] = sa1;
            wb[0] = qpkb[2 * c][0]; wb[1] = qpkb[2 * c][1]; wb[2] = sb0; wb[3] = sb1;
            bf16x8 a32a = __builtin_bit_cast(bf16x8, wa);
            bf16x8 a32b = __builtin_bit_cast(bf16x8, wb);
            #pragma unroll
            for (int db = 0; db < 8; ++db) {
                int d = l15 + 16 * db;
                const char* va = vlds[cur] + d * 128 + ((c * 64 + lg * 16) ^ swzk);
                bf16x8 vf = *(const bf16x8*)va;
                oa[db] = __builtin_amdgcn_mfma_f32_16x16x32_bf16(
                    a32a, vf, oa[db], 0, 0, 0);
                ob[db] = __builtin_amdgcn_mfma_f32_16x16x32_bf16(
                    a32b, vf, ob[db], 0, 0, 0);
            }
        }

        __syncthreads();   // drains prefetch (landed under compute) + swap
    }
#undef STAGE_KV

    lruna += __shfl_xor(lruna, 16);
    lruna += __shfl_xor(lruna, 32);
    lrunb += __shfl_xor(lrunb, 16);
    lrunb += __shfl_xor(lrunb, 32);

    #pragma unroll
    for (int i = 0; i < 4; ++i) {
        float lia = __shfl(lruna, lg * 4 + i);
        float lib = __shfl(lrunb, lg * 4 + i);
        float inva = 1.0f / lia;
        float invb = 1.0f / lib;
        int rowa = b * SEQ + qt * 256 + wid * 16 + lg * 4 + i;
        int rowb = rowa + 128;
        #pragma unroll
        for (int db = 0; db < 8; ++db) {
            int col = h * HDIM + l15 + 16 * db;
            O[(size_t)rowa * DMODEL + col] = (bf16_t)(oa[db][i] * inva);
            O[(size_t)rowb * DMODEL + col] = (bf16_t)(ob[db][i] * invb);
        }
    }
}

// ---------------------------------------------------------------------------
// Launch. Workspace (bf16): Qw 32M | Kw2 8M | Vt 8M | AO 32M | xb 32M |
// wqb 32M | wkvb 16M | wob 32M = 192 MiB.
// ---------------------------------------------------------------------------
extern "C" void kernel_launch(void* const* d_in, const int* in_sizes, int n_in,
                              void* d_out, int out_size, void* d_ws, size_t ws_size,
                              hipStream_t stream)
{
    const float* x  = (const float*)d_in[0];
    const float* wq = (const float*)d_in[1];
    const float* wk = (const float*)d_in[2];
    const float* wv = (const float*)d_in[3];
    const float* wo = (const float*)d_in[4];
    const float* fc = (const float*)d_in[5];
    const float* fs = (const float*)d_in[6];

    const size_t T = (size_t)4096;
    bf16_t* Qw   = (bf16_t*)d_ws;            // [4096][4096]
    bf16_t* Kw2  = Qw   + T * 4096;          // [4096][1024]
    bf16_t* Vt   = Kw2  + T * 1024;          // [1024(kv*128+d)][4096 tok]
    bf16_t* AO   = Vt   + T * 1024;          // [4096][4096]
    bf16_t* xb   = AO   + T * 4096;          // [4096][4096]
    bf16_t* wqb  = xb   + T * 4096;          // [4096][4096]
    bf16_t* wkvb = wqb  + T * 4096;          // [2048][4096]  (wk ; wv)
    bf16_t* wob  = wkvb + T * 2048;          // [4096][4096]

    f2b<<<8192, 256, 0, stream>>>(x,  xb,  4096 * 4096 / 8);
    f2b<<<8192, 256, 0, stream>>>(wq, wqb, 4096 * 4096 / 8);
    f2b<<<2048, 256, 0, stream>>>(wk, wkvb,                       1024 * 4096 / 8);
    f2b<<<2048, 256, 0, stream>>>(wv, wkvb + (size_t)1024 * 4096, 1024 * 4096 / 8);
    f2b<<<8192, 256, 0, stream>>>(wo, wob, 4096 * 4096 / 8);

    gemm256<false><<<256, 512, 0, stream>>>(xb, wqb, Qw, 4096, 4096, 4096, 16);
    gemm_bt<2><<<512, 256, 0, stream>>>(xb, wkvb, Kw2, Vt, 4096, 2048, 4096, 16);

    // Q prescale = (1/sqrt(128)) * log2(e): softmax becomes pure exp2
    rope_kernel<<<8192, 256, 0, stream>>>(Qw,  fc, fs, NHQ,  4096,
                                          0.08838834764831845f * 1.4426950408889634f);
    rope_kernel<<<2048, 256, 0, stream>>>(Kw2, fc, fs, NHKV, 1024, 1.0f);

    attn_kernel<<<512, 512, 0, stream>>>(Qw, Kw2, Vt, AO);

    gemm256<true><<<256, 512, 0, stream>>>(AO, wob, d_out, 4096, 4096, 4096, 16);
}